// Round 15
// baseline (772.968 us; speedup 1.0000x reference)
//
#include <hip/hip_runtime.h>
#include <math.h>

constexpr int HD = 128;     // hidden width per layer
constexpr int DD = 384;     // 3*HD concat
constexpr int KK = 30;      // sort-pool k
constexpr int C1N = 16;
constexpr int C2N = 32;
constexpr int KERN5 = 5;
constexpr int CONVL = 26;   // K - KERN + 1
constexpr int PL = 13;      // pooled length
constexpr int FLAT = 416;   // C2N * PL

typedef __attribute__((ext_vector_type(8))) short bf16x8;   // 8 bf16 in 4 VGPRs (guide §3)
typedef __attribute__((ext_vector_type(4))) float f32x4;

// ---------------- degree count ----------------
__global__ void deg_kernel(const int* __restrict__ col, int* __restrict__ cnt, int E) {
  int e = blockIdx.x * blockDim.x + threadIdx.x;
  if (e < E) atomicAdd(&cnt[col[e]], 1);
}

// ---------------- device-wide exclusive scan, 3 kernels ----------------
__global__ void scan1_kernel(const int* __restrict__ cnt, int* __restrict__ bsum, int N) {
  __shared__ int red[256];
  int t = threadIdx.x, b = blockIdx.x;
  int base = b * 1024 + t * 4;
  int s = 0;
#pragma unroll
  for (int j = 0; j < 4; ++j) { int idx = base + j; if (idx < N) s += cnt[idx]; }
  red[t] = s;
  __syncthreads();
  for (int o = 128; o > 0; o >>= 1) { if (t < o) red[t] += red[t + o]; __syncthreads(); }
  if (t == 0) bsum[b] = red[0];
}

__global__ void scan2_kernel(int* __restrict__ bsum, int nb) {
  __shared__ int s[1024];
  int t = threadIdx.x;
  int v = (t < nb) ? bsum[t] : 0;
  s[t] = v;
  __syncthreads();
  for (int o = 1; o < 1024; o <<= 1) {
    int u = (t >= o) ? s[t - o] : 0;
    __syncthreads();
    s[t] += u;
    __syncthreads();
  }
  if (t < nb) bsum[t] = s[t] - v;   // exclusive
}

// scan3 also produces dis[]
__global__ void scan3_kernel(const int* __restrict__ cnt, const int* __restrict__ bsum,
                             int* __restrict__ offsets, float* __restrict__ dis, int N) {
  __shared__ int red[256];
  int t = threadIdx.x, b = blockIdx.x;
  int base = b * 1024 + t * 4;
  int v[4]; int s = 0;
#pragma unroll
  for (int j = 0; j < 4; ++j) { int idx = base + j; v[j] = (idx < N) ? cnt[idx] : 0; s += v[j]; }
  red[t] = s;
  __syncthreads();
  for (int o = 1; o < 256; o <<= 1) {
    int u = (t >= o) ? red[t - o] : 0;
    __syncthreads();
    red[t] += u;
    __syncthreads();
  }
  int run = bsum[b] + red[t] - s;
#pragma unroll
  for (int j = 0; j < 4; ++j) {
    int idx = base + j;
    if (idx < N) {
      offsets[idx] = run;
      run += v[j];
      dis[idx] = 1.0f / sqrtf((float)(v[j] + 1));
      if (idx == N - 1) offsets[N] = run;
    }
  }
}

// ---------------- CSR fill ----------------
__global__ void fill_kernel(const int* __restrict__ row, const int* __restrict__ col,
                            const int* __restrict__ offsets, int* __restrict__ cursor,
                            int* __restrict__ csr_src, int E) {
  int e = blockIdx.x * blockDim.x + threadIdx.x;
  if (e < E) {
    int c = col[e];
    int p = offsets[c] + atomicAdd(&cursor[c], 1);
    csr_src[p] = row[e];
  }
}

// ---------------- split-bf16 helpers ----------------
__device__ __forceinline__ ushort bf16_rne(float x) {
  uint32_t bits = __float_as_uint(x);
  uint32_t r = bits + 0x7FFFu + ((bits >> 16) & 1u);
  return (ushort)(r >> 16);
}

// 3-way W^T prep: W = Wh + Wm + Wl (each bf16), stored transposed [col][k].
__global__ void wprep_kernel(const float* __restrict__ W, ushort* __restrict__ WhT,
                             ushort* __restrict__ WmT, ushort* __restrict__ WlT) {
  int t = blockIdx.x * 256 + threadIdx.x;   // 16384
  int k = t >> 7, col = t & 127;
  float x = W[k * 128 + col];
  ushort h = bf16_rne(x);
  float r1 = x - __uint_as_float(((uint32_t)h) << 16);      // exact
  ushort m = bf16_rne(r1);
  float r2 = r1 - __uint_as_float(((uint32_t)m) << 16);     // exact
  ushort l = bf16_rne(r2);
  WhT[col * 128 + k] = h;
  WmT[col * 128 + k] = m;
  WlT[col * 128 + k] = l;
}

// ---------------- layer 0: x1 = tanh(agg(W0[z]) + b0), HALF-WAVE per node ----------------
__global__ __launch_bounds__(256) void agg0_kernel(
    const int* __restrict__ z, const int* __restrict__ offsets,
    const int* __restrict__ csr_src, const float* __restrict__ dis,
    const float* __restrict__ W0, const float* __restrict__ b0,
    float* __restrict__ x1, int N) {
  int hw = (blockIdx.x * blockDim.x + threadIdx.x) >> 5;
  int lane = threadIdx.x & 31;
  if (hw >= N) return;
  int i = hw;
  int c0 = lane * 4;
  float di = dis[i];
  int beg = offsets[i], end = offsets[i + 1];
  float ax = 0.f, ay = 0.f, az = 0.f, aw = 0.f;
  int e = beg;
  for (; e + 8 <= end; e += 8) {
    int s0 = csr_src[e],     s1 = csr_src[e + 1], s2 = csr_src[e + 2], s3 = csr_src[e + 3];
    int s4 = csr_src[e + 4], s5 = csr_src[e + 5], s6 = csr_src[e + 6], s7 = csr_src[e + 7];
    float w0 = dis[s0], w1 = dis[s1], w2 = dis[s2], w3 = dis[s3];
    float w4 = dis[s4], w5 = dis[s5], w6 = dis[s6], w7 = dis[s7];
    const float4 y0 = *(const float4*)(W0 + (size_t)z[s0] * HD + c0);
    const float4 y1 = *(const float4*)(W0 + (size_t)z[s1] * HD + c0);
    const float4 y2 = *(const float4*)(W0 + (size_t)z[s2] * HD + c0);
    const float4 y3 = *(const float4*)(W0 + (size_t)z[s3] * HD + c0);
    const float4 y4 = *(const float4*)(W0 + (size_t)z[s4] * HD + c0);
    const float4 y5 = *(const float4*)(W0 + (size_t)z[s5] * HD + c0);
    const float4 y6 = *(const float4*)(W0 + (size_t)z[s6] * HD + c0);
    const float4 y7 = *(const float4*)(W0 + (size_t)z[s7] * HD + c0);
    ax = fmaf(w0, y0.x, fmaf(w1, y1.x, fmaf(w2, y2.x, fmaf(w3, y3.x, ax))));
    ay = fmaf(w0, y0.y, fmaf(w1, y1.y, fmaf(w2, y2.y, fmaf(w3, y3.y, ay))));
    az = fmaf(w0, y0.z, fmaf(w1, y1.z, fmaf(w2, y2.z, fmaf(w3, y3.z, az))));
    aw = fmaf(w0, y0.w, fmaf(w1, y1.w, fmaf(w2, y2.w, fmaf(w3, y3.w, aw))));
    ax = fmaf(w4, y4.x, fmaf(w5, y5.x, fmaf(w6, y6.x, fmaf(w7, y7.x, ax))));
    ay = fmaf(w4, y4.y, fmaf(w5, y5.y, fmaf(w6, y6.y, fmaf(w7, y7.y, ay))));
    az = fmaf(w4, y4.z, fmaf(w5, y5.z, fmaf(w6, y6.z, fmaf(w7, y7.z, az))));
    aw = fmaf(w4, y4.w, fmaf(w5, y5.w, fmaf(w6, y6.w, fmaf(w7, y7.w, aw))));
  }
  for (; e + 4 <= end; e += 4) {
    int s0 = csr_src[e], s1 = csr_src[e + 1], s2 = csr_src[e + 2], s3 = csr_src[e + 3];
    float w0 = dis[s0], w1 = dis[s1], w2 = dis[s2], w3 = dis[s3];
    const float4 y0 = *(const float4*)(W0 + (size_t)z[s0] * HD + c0);
    const float4 y1 = *(const float4*)(W0 + (size_t)z[s1] * HD + c0);
    const float4 y2 = *(const float4*)(W0 + (size_t)z[s2] * HD + c0);
    const float4 y3 = *(const float4*)(W0 + (size_t)z[s3] * HD + c0);
    ax = fmaf(w0, y0.x, fmaf(w1, y1.x, fmaf(w2, y2.x, fmaf(w3, y3.x, ax))));
    ay = fmaf(w0, y0.y, fmaf(w1, y1.y, fmaf(w2, y2.y, fmaf(w3, y3.y, ay))));
    az = fmaf(w0, y0.z, fmaf(w1, y1.z, fmaf(w2, y2.z, fmaf(w3, y3.z, az))));
    aw = fmaf(w0, y0.w, fmaf(w1, y1.w, fmaf(w2, y2.w, fmaf(w3, y3.w, aw))));
  }
  for (; e < end; ++e) {
    int s = csr_src[e];
    float w = dis[s];
    const float4 ys = *(const float4*)(W0 + (size_t)z[s] * HD + c0);
    ax = fmaf(w, ys.x, ax);
    ay = fmaf(w, ys.y, ay);
    az = fmaf(w, ys.z, az);
    aw = fmaf(w, ys.w, aw);
  }
  const float4 yi = *(const float4*)(W0 + (size_t)z[i] * HD + c0);
  const float4 bb = *(const float4*)(b0 + c0);
  float inv = di * di;
  float4 o = make_float4(tanhf(di * ax + inv * yi.x + bb.x),
                         tanhf(di * ay + inv * yi.y + bb.y),
                         tanhf(di * az + inv * yi.z + bb.z),
                         tanhf(di * aw + inv * yi.w + bb.w));
  *(float4*)(x1 + (size_t)i * HD + c0) = o;
}

// ---------------- pure aggregation, HALF-WAVE per node (BW-ceiling config) ----------------
__global__ __launch_bounds__(256) void agg_kernel(
    const float* __restrict__ x, const int* __restrict__ offsets,
    const int* __restrict__ csr_src, const float* __restrict__ dis,
    float* __restrict__ T, int N) {
  int hw = (blockIdx.x * blockDim.x + threadIdx.x) >> 5;
  int lane = threadIdx.x & 31;
  if (hw >= N) return;
  int i = hw;
  int c0 = lane * 4;
  float di = dis[i];
  int beg = offsets[i], end = offsets[i + 1];
  float ax = 0.f, ay = 0.f, az = 0.f, aw = 0.f;
  int e = beg;
  for (; e + 8 <= end; e += 8) {
    int s0 = csr_src[e],     s1 = csr_src[e + 1], s2 = csr_src[e + 2], s3 = csr_src[e + 3];
    int s4 = csr_src[e + 4], s5 = csr_src[e + 5], s6 = csr_src[e + 6], s7 = csr_src[e + 7];
    float w0 = dis[s0], w1 = dis[s1], w2 = dis[s2], w3 = dis[s3];
    float w4 = dis[s4], w5 = dis[s5], w6 = dis[s6], w7 = dis[s7];
    const float4 y0 = *(const float4*)(x + (size_t)s0 * HD + c0);
    const float4 y1 = *(const float4*)(x + (size_t)s1 * HD + c0);
    const float4 y2 = *(const float4*)(x + (size_t)s2 * HD + c0);
    const float4 y3 = *(const float4*)(x + (size_t)s3 * HD + c0);
    const float4 y4 = *(const float4*)(x + (size_t)s4 * HD + c0);
    const float4 y5 = *(const float4*)(x + (size_t)s5 * HD + c0);
    const float4 y6 = *(const float4*)(x + (size_t)s6 * HD + c0);
    const float4 y7 = *(const float4*)(x + (size_t)s7 * HD + c0);
    ax = fmaf(w0, y0.x, fmaf(w1, y1.x, fmaf(w2, y2.x, fmaf(w3, y3.x, ax))));
    ay = fmaf(w0, y0.y, fmaf(w1, y1.y, fmaf(w2, y2.y, fmaf(w3, y3.y, ay))));
    az = fmaf(w0, y0.z, fmaf(w1, y1.z, fmaf(w2, y2.z, fmaf(w3, y3.z, az))));
    aw = fmaf(w0, y0.w, fmaf(w1, y1.w, fmaf(w2, y2.w, fmaf(w3, y3.w, aw))));
    ax = fmaf(w4, y4.x, fmaf(w5, y5.x, fmaf(w6, y6.x, fmaf(w7, y7.x, ax))));
    ay = fmaf(w4, y4.y, fmaf(w5, y5.y, fmaf(w6, y6.y, fmaf(w7, y7.y, ay))));
    az = fmaf(w4, y4.z, fmaf(w5, y5.z, fmaf(w6, y6.z, fmaf(w7, y7.z, az))));
    aw = fmaf(w4, y4.w, fmaf(w5, y5.w, fmaf(w6, y6.w, fmaf(w7, y7.w, aw))));
  }
  for (; e + 4 <= end; e += 4) {
    int s0 = csr_src[e], s1 = csr_src[e + 1], s2 = csr_src[e + 2], s3 = csr_src[e + 3];
    float w0 = dis[s0], w1 = dis[s1], w2 = dis[s2], w3 = dis[s3];
    const float4 y0 = *(const float4*)(x + (size_t)s0 * HD + c0);
    const float4 y1 = *(const float4*)(x + (size_t)s1 * HD + c0);
    const float4 y2 = *(const float4*)(x + (size_t)s2 * HD + c0);
    const float4 y3 = *(const float4*)(x + (size_t)s3 * HD + c0);
    ax = fmaf(w0, y0.x, fmaf(w1, y1.x, fmaf(w2, y2.x, fmaf(w3, y3.x, ax))));
    ay = fmaf(w0, y0.y, fmaf(w1, y1.y, fmaf(w2, y2.y, fmaf(w3, y3.y, ay))));
    az = fmaf(w0, y0.z, fmaf(w1, y1.z, fmaf(w2, y2.z, fmaf(w3, y3.z, az))));
    aw = fmaf(w0, y0.w, fmaf(w1, y1.w, fmaf(w2, y2.w, fmaf(w3, y3.w, aw))));
  }
  for (; e < end; ++e) {
    int s = csr_src[e];
    float w = dis[s];
    const float4 ys = *(const float4*)(x + (size_t)s * HD + c0);
    ax = fmaf(w, ys.x, ax);
    ay = fmaf(w, ys.y, ay);
    az = fmaf(w, ys.z, az);
    aw = fmaf(w, ys.w, aw);
  }
  const float4 xi = *(const float4*)(x + (size_t)i * HD + c0);
  float inv = di * di;
  float4 o = make_float4(di * ax + inv * xi.x, di * ay + inv * xi.y,
                         di * az + inv * xi.z, di * aw + inv * xi.w);
  *(float4*)(T + (size_t)i * HD + c0) = o;
}

// ---------------- 3-way-split bf16 MFMA GEMM: T = tanh(T @ W + b), in-place ----------------
// x = h + m + l (RNE bf16 terms; h~1, m~2^-9, l~2^-18 rel). Keep the 6 products >= 2^-18:
// hh + hm + mh + hl + mm + lh; dropped (ml, lm, ll) ~ 2^-27 rel -> f32-level accuracy.
// (R14's 2-term split measured 67x f32 error == the predicted 2^-18/2^-24 = 64x; this
// restores the missing 6 bits.)
// Fragment layouts (guide §3, m89-verified C/D):
//   A: row = lane&15, k = 8*(lane>>4)+j ; B: col = lane&15, same k (from W^T planes);
//   D: col = lane&15, row = 4*(lane>>4)+r.
__global__ __launch_bounds__(512) void gemm_mfma_kernel(
    float* __restrict__ T, const ushort* __restrict__ WhT, const ushort* __restrict__ WmT,
    const ushort* __restrict__ WlT, const float* __restrict__ b, int N) {
  __shared__ ushort Ah[128][40];   // 80B row stride: 16B-aligned b128, ~2-way banks (free)
  __shared__ ushort Am[128][40];
  __shared__ ushort Al[128][40];
  int t = threadIdx.x;
  int r0 = blockIdx.x * 128;
  int w = t >> 6, l = t & 63;
  int lr = l & 15, lg = l >> 4;
  f32x4 acc[8];
#pragma unroll
  for (int n = 0; n < 8; ++n) acc[n] = (f32x4){0.f, 0.f, 0.f, 0.f};

  for (int kb = 0; kb < 4; ++kb) {
    __syncthreads();   // protect A-buffers from previous iteration's readers
    {
      // stage + 3-way split: thread t -> row t>>2, 8 cols at (t&3)*8 of this K-slice
      int r = t >> 2, c8 = (t & 3) * 8;
      const float* src = T + (size_t)(r0 + r) * HD + kb * 32 + c8;
      float4 v0 = *(const float4*)src;
      float4 v1 = *(const float4*)(src + 4);
      float xs[8] = {v0.x, v0.y, v0.z, v0.w, v1.x, v1.y, v1.z, v1.w};
      uint32_t hp[4], mp[4], lp[4];
#pragma unroll
      for (int j = 0; j < 4; ++j) {
        ushort h0 = bf16_rne(xs[2 * j]);
        ushort h1 = bf16_rne(xs[2 * j + 1]);
        float r10 = xs[2 * j]     - __uint_as_float(((uint32_t)h0) << 16);  // exact
        float r11 = xs[2 * j + 1] - __uint_as_float(((uint32_t)h1) << 16);
        ushort m0 = bf16_rne(r10);
        ushort m1 = bf16_rne(r11);
        float r20 = r10 - __uint_as_float(((uint32_t)m0) << 16);            // exact
        float r21 = r11 - __uint_as_float(((uint32_t)m1) << 16);
        ushort l0 = bf16_rne(r20);
        ushort l1 = bf16_rne(r21);
        hp[j] = (uint32_t)h0 | ((uint32_t)h1 << 16);
        mp[j] = (uint32_t)m0 | ((uint32_t)m1 << 16);
        lp[j] = (uint32_t)l0 | ((uint32_t)l1 << 16);
      }
      uint32_t* ah = (uint32_t*)&Ah[r][c8];
      uint32_t* am = (uint32_t*)&Am[r][c8];
      uint32_t* al = (uint32_t*)&Al[r][c8];
#pragma unroll
      for (int j = 0; j < 4; ++j) { ah[j] = hp[j]; am[j] = mp[j]; al[j] = lp[j]; }
    }
    __syncthreads();

    bf16x8 fa_h = *(const bf16x8*)(&Ah[16 * w + lr][8 * lg]);
    bf16x8 fa_m = *(const bf16x8*)(&Am[16 * w + lr][8 * lg]);
    bf16x8 fa_l = *(const bf16x8*)(&Al[16 * w + lr][8 * lg]);
    int kk = kb * 32 + 8 * lg;
#pragma unroll
    for (int n = 0; n < 8; ++n) {
      bf16x8 fb_h = *(const bf16x8*)(WhT + (size_t)(16 * n + lr) * 128 + kk);
      bf16x8 fb_m = *(const bf16x8*)(WmT + (size_t)(16 * n + lr) * 128 + kk);
      bf16x8 fb_l = *(const bf16x8*)(WlT + (size_t)(16 * n + lr) * 128 + kk);
      acc[n] = __builtin_amdgcn_mfma_f32_16x16x32_bf16(fa_h, fb_h, acc[n], 0, 0, 0);
      acc[n] = __builtin_amdgcn_mfma_f32_16x16x32_bf16(fa_h, fb_m, acc[n], 0, 0, 0);
      acc[n] = __builtin_amdgcn_mfma_f32_16x16x32_bf16(fa_m, fb_h, acc[n], 0, 0, 0);
      acc[n] = __builtin_amdgcn_mfma_f32_16x16x32_bf16(fa_h, fb_l, acc[n], 0, 0, 0);
      acc[n] = __builtin_amdgcn_mfma_f32_16x16x32_bf16(fa_m, fb_m, acc[n], 0, 0, 0);
      acc[n] = __builtin_amdgcn_mfma_f32_16x16x32_bf16(fa_l, fb_h, acc[n], 0, 0, 0);
    }
  }

  // epilogue: bias + tanh; D[col=lr][row=4*lg+r] per 16x16 tile. In-place safe:
  // all reads of this block's rows completed in the kb loop.
#pragma unroll
  for (int n = 0; n < 8; ++n) {
    float bc = b[16 * n + lr];
#pragma unroll
    for (int r = 0; r < 4; ++r) {
      int row = r0 + 16 * w + 4 * lg + r;
      T[(size_t)row * HD + 16 * n + lr] = tanhf(acc[n][r] + bc);
    }
  }
}

// ---------------- per-graph start offsets ----------------
__global__ void gstart_kernel(const int* __restrict__ batch, int* __restrict__ gstart,
                              int N, int B) {
  int g = blockIdx.x * blockDim.x + threadIdx.x;
  if (g > B) return;
  int lo = 0, hi = N;
  while (lo < hi) { int mid = (lo + hi) >> 1; if (batch[mid] < g) lo = mid + 1; else hi = mid; }
  gstart[g] = lo;
}

// ---------------- sort-pool + conv head, one block per graph, 512 threads ----------------
__global__ __launch_bounds__(512) void head_kernel(
    const float* __restrict__ X1, const float* __restrict__ X2, const float* __restrict__ X3,
    const int* __restrict__ gstart,
    const float* __restrict__ Wc1, const float* __restrict__ bc1,
    const float* __restrict__ Wc2, const float* __restrict__ bc2,
    const float* __restrict__ g1, const float* __restrict__ be1,
    const float* __restrict__ g2, const float* __restrict__ be2,
    const float* __restrict__ rm1, const float* __restrict__ rv1,
    const float* __restrict__ rm2, const float* __restrict__ rv2,
    const float* __restrict__ Wl1, const float* __restrict__ bl1,
    const float* __restrict__ Wl2, const float* __restrict__ bl2,
    float* __restrict__ out) {
  constexpr int MAXC = 512;
  __shared__ float vals[MAXC];
  __shared__ int   sel[KK];
  __shared__ float ph[KK][385];
  __shared__ float h1b[C1N][KK + 1];
  float* h2b  = &ph[0][0];
  float* pp   = &ph[0][0] + 832;
  float* part = &ph[0][0] + 1248;
  float* l1v  = &ph[0][0] + 1760;

  int g = blockIdx.x, t = threadIdx.x;
  int start = gstart[g];
  int count = gstart[g + 1] - start;
  if (count > MAXC) count = MAXC;
  int kk = count < KK ? count : KK;

  for (int i = t; i < count; i += 512)
    vals[i] = X3[(size_t)(start + i) * HD + (HD - 1)];
  __syncthreads();
  if (t < count) {
    float vi = vals[t];
    int rank = 0;
    for (int j = 0; j < count; ++j) {
      float vj = vals[j];
      rank += (vj > vi) || (vj == vi && j < t);
    }
    if (rank < KK) sel[rank] = t;
  }
  __syncthreads();

  for (int l = t; l < KK * DD; l += 512) {
    int r = l / DD, d = l - r * DD;
    float v = 0.f;
    if (r < kk) {
      size_t n = (size_t)(start + sel[r]);
      v = (d < HD) ? X1[n * HD + d]
        : (d < 2 * HD) ? X2[n * HD + (d - HD)]
                       : X3[n * HD + (d - 2 * HD)];
    }
    ph[r][d] = v;
  }
  __syncthreads();

  if (t < C1N * KK) {
    int c = t / KK, k = t - c * KK;
    const float* w = Wc1 + c * DD;
    float s = bc1[c];
    for (int d = 0; d < DD; ++d) s = fmaf(ph[k][d], w[d], s);
    s = fmaxf(s, 0.f);
    float sc = g1[c] * rsqrtf(rv1[c] + 1e-5f);
    h1b[c][k] = (s - rm1[c]) * sc + be1[c];
  }
  __syncthreads();

  for (int l = t; l < C2N * CONVL; l += 512) {
    int o = l / CONVL, tt = l - o * CONVL;
    float s = bc2[o];
    const float* w = Wc2 + o * (C1N * KERN5);
#pragma unroll
    for (int c = 0; c < C1N; ++c)
#pragma unroll
      for (int q = 0; q < KERN5; ++q)
        s = fmaf(h1b[c][tt + q], w[c * KERN5 + q], s);
    s = fmaxf(s, 0.f);
    float sc = g2[o] * rsqrtf(rv2[o] + 1e-5f);
    h2b[o * CONVL + tt] = (s - rm2[o]) * sc + be2[o];
  }
  __syncthreads();

  if (t < FLAT) {
    int o = t / PL, u = t - o * PL;
    pp[t] = fmaxf(h2b[o * CONVL + 2 * u], h2b[o * CONVL + 2 * u + 1]);
  }
  __syncthreads();

  {
    int j = t & 127, h = t >> 7;
    const int Q = FLAT / 4;
    const float* w = Wl1 + (size_t)j * FLAT + h * Q;
    float s = (h == 0) ? bl1[j] : 0.f;
    for (int f = 0; f < Q; ++f) s = fmaf(pp[h * Q + f], w[f], s);
    part[t] = s;
  }
  __syncthreads();
  if (t < 128) l1v[t] = fmaxf(part[t] + part[t + 128] + part[t + 256] + part[t + 384], 0.f);
  __syncthreads();

  if (t < 64) {
    float s = l1v[t] * Wl2[t] + l1v[t + 64] * Wl2[t + 64];
#pragma unroll
    for (int o2 = 32; o2 > 0; o2 >>= 1) s += __shfl_down(s, o2);
    if (t == 0) out[g] = s + bl2[0];
  }
}

extern "C" void kernel_launch(void* const* d_in, const int* in_sizes, int n_in,
                              void* d_out, int out_size, void* d_ws, size_t ws_size,
                              hipStream_t stream) {
  const int*   z    = (const int*)d_in[0];
  const int*   ei   = (const int*)d_in[1];
  const int*   batch= (const int*)d_in[2];
  const float* W0   = (const float*)d_in[3];
  const float* b0   = (const float*)d_in[4];
  const float* W1   = (const float*)d_in[5];
  const float* b1   = (const float*)d_in[6];
  const float* W2   = (const float*)d_in[7];
  const float* b2   = (const float*)d_in[8];
  const float* Wc1  = (const float*)d_in[9];
  const float* bc1  = (const float*)d_in[10];
  const float* Wc2  = (const float*)d_in[11];
  const float* bc2  = (const float*)d_in[12];
  const float* g1   = (const float*)d_in[13];
  const float* be1  = (const float*)d_in[14];
  const float* g2   = (const float*)d_in[15];
  const float* be2  = (const float*)d_in[16];
  const float* Wl1  = (const float*)d_in[17];
  const float* bl1  = (const float*)d_in[18];
  const float* Wl2  = (const float*)d_in[19];
  const float* bl2  = (const float*)d_in[20];
  const float* rm1  = (const float*)d_in[21];
  const float* rv1  = (const float*)d_in[22];
  const float* rm2  = (const float*)d_in[23];
  const float* rv2  = (const float*)d_in[24];

  const int N = in_sizes[0];
  const int E = in_sizes[1] / 2;
  const int B = out_size;
  const int* rowp = ei;       // edge_index[0] = source
  const int* colp = ei + E;   // edge_index[1] = target

  char* base = (char*)d_ws;
  size_t off = 0;
  auto alloc = [&](size_t bytes) -> void* {
    void* p = base + off;
    off += (bytes + 255) & ~(size_t)255;
    return p;
  };
  int*    cnt     = (int*)alloc((size_t)N * 4);
  int*    offsets = (int*)alloc(((size_t)N + 1) * 4);
  int*    cursor  = (int*)alloc((size_t)N * 4);
  int*    csr_src = (int*)alloc((size_t)E * 4);
  float*  dis     = (float*)alloc((size_t)N * 4);
  int*    gstart  = (int*)alloc(((size_t)B + 1) * 4);
  int*    bsum    = (int*)alloc(1024 * 4);
  ushort* WhT1    = (ushort*)alloc(128 * 128 * 2);
  ushort* WmT1    = (ushort*)alloc(128 * 128 * 2);
  ushort* WlT1    = (ushort*)alloc(128 * 128 * 2);
  ushort* WhT2    = (ushort*)alloc(128 * 128 * 2);
  ushort* WmT2    = (ushort*)alloc(128 * 128 * 2);
  ushort* WlT2    = (ushort*)alloc(128 * 128 * 2);
  float*  X1      = (float*)alloc((size_t)N * HD * 4);
  float*  X2      = (float*)alloc((size_t)N * HD * 4);
  float*  X3      = (float*)alloc((size_t)N * HD * 4);
  (void)ws_size; (void)n_in;

  hipMemsetAsync(cnt, 0, (size_t)N * 4, stream);
  hipMemsetAsync(cursor, 0, (size_t)N * 4, stream);

  const int nb = (N + 1023) / 1024;
  deg_kernel<<<(E + 255) / 256, 256, 0, stream>>>(colp, cnt, E);
  scan1_kernel<<<nb, 256, 0, stream>>>(cnt, bsum, N);
  scan2_kernel<<<1, 1024, 0, stream>>>(bsum, nb);
  scan3_kernel<<<nb, 256, 0, stream>>>(cnt, bsum, offsets, dis, N);
  fill_kernel<<<(E + 255) / 256, 256, 0, stream>>>(rowp, colp, offsets, cursor, csr_src, E);
  wprep_kernel<<<64, 256, 0, stream>>>(W1, WhT1, WmT1, WlT1);
  wprep_kernel<<<64, 256, 0, stream>>>(W2, WhT2, WmT2, WlT2);

  // layer 0: onehot(z)@W0 == W0[z], fused into aggregation, tanh inside
  agg0_kernel<<<N / 8, 256, 0, stream>>>(z, offsets, csr_src, dis, W0, b0, X1, N);
  // layer 1: aggregate-first (half-wave gather), then in-place 3-way-split MFMA GEMM
  agg_kernel<<<N / 8, 256, 0, stream>>>(X1, offsets, csr_src, dis, X2, N);
  gemm_mfma_kernel<<<N / 128, 512, 0, stream>>>(X2, WhT1, WmT1, WlT1, b1, N);
  // layer 2
  agg_kernel<<<N / 8, 256, 0, stream>>>(X2, offsets, csr_src, dis, X3, N);
  gemm_mfma_kernel<<<N / 128, 512, 0, stream>>>(X3, WhT2, WmT2, WlT2, b2, N);

  gstart_kernel<<<(B + 1 + 255) / 256, 256, 0, stream>>>(batch, gstart, N, B);
  head_kernel<<<B, 512, 0, stream>>>(X1, X2, X3, gstart, Wc1, bc1, Wc2, bc2, g1, be1, g2, be2,
                                     rm1, rv1, rm2, rv2, Wl1, bl1, Wl2, bl2, (float*)d_out);
}

// Round 16
// 762.617 us; speedup vs baseline: 1.0136x; 1.0136x over previous
//
#include <hip/hip_runtime.h>
#include <math.h>

constexpr int HD = 128;     // hidden width per layer
constexpr int DD = 384;     // 3*HD concat
constexpr int KK = 30;      // sort-pool k
constexpr int C1N = 16;
constexpr int C2N = 32;
constexpr int KERN5 = 5;
constexpr int CONVL = 26;   // K - KERN + 1
constexpr int PL = 13;      // pooled length
constexpr int FLAT = 416;   // C2N * PL

typedef __attribute__((ext_vector_type(8))) short bf16x8;   // 8 bf16 in 4 VGPRs (guide §3)
typedef __attribute__((ext_vector_type(4))) float f32x4;

// ---------------- degree count ----------------
__global__ void deg_kernel(const int* __restrict__ col, int* __restrict__ cnt, int E) {
  int e = blockIdx.x * blockDim.x + threadIdx.x;
  if (e < E) atomicAdd(&cnt[col[e]], 1);
}

// ---------------- device-wide exclusive scan, 3 kernels ----------------
__global__ void scan1_kernel(const int* __restrict__ cnt, int* __restrict__ bsum, int N) {
  __shared__ int red[256];
  int t = threadIdx.x, b = blockIdx.x;
  int base = b * 1024 + t * 4;
  int s = 0;
#pragma unroll
  for (int j = 0; j < 4; ++j) { int idx = base + j; if (idx < N) s += cnt[idx]; }
  red[t] = s;
  __syncthreads();
  for (int o = 128; o > 0; o >>= 1) { if (t < o) red[t] += red[t + o]; __syncthreads(); }
  if (t == 0) bsum[b] = red[0];
}

__global__ void scan2_kernel(int* __restrict__ bsum, int nb) {
  __shared__ int s[1024];
  int t = threadIdx.x;
  int v = (t < nb) ? bsum[t] : 0;
  s[t] = v;
  __syncthreads();
  for (int o = 1; o < 1024; o <<= 1) {
    int u = (t >= o) ? s[t - o] : 0;
    __syncthreads();
    s[t] += u;
    __syncthreads();
  }
  if (t < nb) bsum[t] = s[t] - v;   // exclusive
}

// scan3 also produces dis[]
__global__ void scan3_kernel(const int* __restrict__ cnt, const int* __restrict__ bsum,
                             int* __restrict__ offsets, float* __restrict__ dis, int N) {
  __shared__ int red[256];
  int t = threadIdx.x, b = blockIdx.x;
  int base = b * 1024 + t * 4;
  int v[4]; int s = 0;
#pragma unroll
  for (int j = 0; j < 4; ++j) { int idx = base + j; v[j] = (idx < N) ? cnt[idx] : 0; s += v[j]; }
  red[t] = s;
  __syncthreads();
  for (int o = 1; o < 256; o <<= 1) {
    int u = (t >= o) ? red[t - o] : 0;
    __syncthreads();
    red[t] += u;
    __syncthreads();
  }
  int run = bsum[b] + red[t] - s;
#pragma unroll
  for (int j = 0; j < 4; ++j) {
    int idx = base + j;
    if (idx < N) {
      offsets[idx] = run;
      run += v[j];
      dis[idx] = 1.0f / sqrtf((float)(v[j] + 1));
      if (idx == N - 1) offsets[N] = run;
    }
  }
}

// ---------------- CSR fill ----------------
__global__ void fill_kernel(const int* __restrict__ row, const int* __restrict__ col,
                            const int* __restrict__ offsets, int* __restrict__ cursor,
                            int* __restrict__ csr_src, int E) {
  int e = blockIdx.x * blockDim.x + threadIdx.x;
  if (e < E) {
    int c = col[e];
    int p = offsets[c] + atomicAdd(&cursor[c], 1);
    csr_src[p] = row[e];
  }
}

// ---------------- split-bf16 helpers ----------------
__device__ __forceinline__ ushort bf16_rne(float x) {
  uint32_t bits = __float_as_uint(x);
  uint32_t r = bits + 0x7FFFu + ((bits >> 16) & 1u);
  return (ushort)(r >> 16);
}

// 3-way W^T prep: W = Wh + Wm + Wl (each bf16), stored transposed [col][k].
__global__ void wprep_kernel(const float* __restrict__ W, ushort* __restrict__ WhT,
                             ushort* __restrict__ WmT, ushort* __restrict__ WlT) {
  int t = blockIdx.x * 256 + threadIdx.x;   // 16384
  int k = t >> 7, col = t & 127;
  float x = W[k * 128 + col];
  ushort h = bf16_rne(x);
  float r1 = x - __uint_as_float(((uint32_t)h) << 16);      // exact
  ushort m = bf16_rne(r1);
  float r2 = r1 - __uint_as_float(((uint32_t)m) << 16);     // exact
  ushort l = bf16_rne(r2);
  WhT[col * 128 + k] = h;
  WmT[col * 128 + k] = m;
  WlT[col * 128 + k] = l;
}

// ---------------- layer 0: x1 = tanh(agg(W0[z]) + b0), HALF-WAVE per node ----------------
__global__ __launch_bounds__(256) void agg0_kernel(
    const int* __restrict__ z, const int* __restrict__ offsets,
    const int* __restrict__ csr_src, const float* __restrict__ dis,
    const float* __restrict__ W0, const float* __restrict__ b0,
    float* __restrict__ x1, int N) {
  int hw = (blockIdx.x * blockDim.x + threadIdx.x) >> 5;
  int lane = threadIdx.x & 31;
  if (hw >= N) return;
  int i = hw;
  int c0 = lane * 4;
  float di = dis[i];
  int beg = offsets[i], end = offsets[i + 1];
  float ax = 0.f, ay = 0.f, az = 0.f, aw = 0.f;
  int e = beg;
  for (; e + 8 <= end; e += 8) {
    int s0 = csr_src[e],     s1 = csr_src[e + 1], s2 = csr_src[e + 2], s3 = csr_src[e + 3];
    int s4 = csr_src[e + 4], s5 = csr_src[e + 5], s6 = csr_src[e + 6], s7 = csr_src[e + 7];
    float w0 = dis[s0], w1 = dis[s1], w2 = dis[s2], w3 = dis[s3];
    float w4 = dis[s4], w5 = dis[s5], w6 = dis[s6], w7 = dis[s7];
    const float4 y0 = *(const float4*)(W0 + (size_t)z[s0] * HD + c0);
    const float4 y1 = *(const float4*)(W0 + (size_t)z[s1] * HD + c0);
    const float4 y2 = *(const float4*)(W0 + (size_t)z[s2] * HD + c0);
    const float4 y3 = *(const float4*)(W0 + (size_t)z[s3] * HD + c0);
    const float4 y4 = *(const float4*)(W0 + (size_t)z[s4] * HD + c0);
    const float4 y5 = *(const float4*)(W0 + (size_t)z[s5] * HD + c0);
    const float4 y6 = *(const float4*)(W0 + (size_t)z[s6] * HD + c0);
    const float4 y7 = *(const float4*)(W0 + (size_t)z[s7] * HD + c0);
    ax = fmaf(w0, y0.x, fmaf(w1, y1.x, fmaf(w2, y2.x, fmaf(w3, y3.x, ax))));
    ay = fmaf(w0, y0.y, fmaf(w1, y1.y, fmaf(w2, y2.y, fmaf(w3, y3.y, ay))));
    az = fmaf(w0, y0.z, fmaf(w1, y1.z, fmaf(w2, y2.z, fmaf(w3, y3.z, az))));
    aw = fmaf(w0, y0.w, fmaf(w1, y1.w, fmaf(w2, y2.w, fmaf(w3, y3.w, aw))));
    ax = fmaf(w4, y4.x, fmaf(w5, y5.x, fmaf(w6, y6.x, fmaf(w7, y7.x, ax))));
    ay = fmaf(w4, y4.y, fmaf(w5, y5.y, fmaf(w6, y6.y, fmaf(w7, y7.y, ay))));
    az = fmaf(w4, y4.z, fmaf(w5, y5.z, fmaf(w6, y6.z, fmaf(w7, y7.z, az))));
    aw = fmaf(w4, y4.w, fmaf(w5, y5.w, fmaf(w6, y6.w, fmaf(w7, y7.w, aw))));
  }
  for (; e + 4 <= end; e += 4) {
    int s0 = csr_src[e], s1 = csr_src[e + 1], s2 = csr_src[e + 2], s3 = csr_src[e + 3];
    float w0 = dis[s0], w1 = dis[s1], w2 = dis[s2], w3 = dis[s3];
    const float4 y0 = *(const float4*)(W0 + (size_t)z[s0] * HD + c0);
    const float4 y1 = *(const float4*)(W0 + (size_t)z[s1] * HD + c0);
    const float4 y2 = *(const float4*)(W0 + (size_t)z[s2] * HD + c0);
    const float4 y3 = *(const float4*)(W0 + (size_t)z[s3] * HD + c0);
    ax = fmaf(w0, y0.x, fmaf(w1, y1.x, fmaf(w2, y2.x, fmaf(w3, y3.x, ax))));
    ay = fmaf(w0, y0.y, fmaf(w1, y1.y, fmaf(w2, y2.y, fmaf(w3, y3.y, ay))));
    az = fmaf(w0, y0.z, fmaf(w1, y1.z, fmaf(w2, y2.z, fmaf(w3, y3.z, az))));
    aw = fmaf(w0, y0.w, fmaf(w1, y1.w, fmaf(w2, y2.w, fmaf(w3, y3.w, aw))));
  }
  for (; e < end; ++e) {
    int s = csr_src[e];
    float w = dis[s];
    const float4 ys = *(const float4*)(W0 + (size_t)z[s] * HD + c0);
    ax = fmaf(w, ys.x, ax);
    ay = fmaf(w, ys.y, ay);
    az = fmaf(w, ys.z, az);
    aw = fmaf(w, ys.w, aw);
  }
  const float4 yi = *(const float4*)(W0 + (size_t)z[i] * HD + c0);
  const float4 bb = *(const float4*)(b0 + c0);
  float inv = di * di;
  float4 o = make_float4(tanhf(di * ax + inv * yi.x + bb.x),
                         tanhf(di * ay + inv * yi.y + bb.y),
                         tanhf(di * az + inv * yi.z + bb.z),
                         tanhf(di * aw + inv * yi.w + bb.w));
  *(float4*)(x1 + (size_t)i * HD + c0) = o;
}

// ---------------- pure aggregation, HALF-WAVE per node (BW-ceiling config) ----------------
__global__ __launch_bounds__(256) void agg_kernel(
    const float* __restrict__ x, const int* __restrict__ offsets,
    const int* __restrict__ csr_src, const float* __restrict__ dis,
    float* __restrict__ T, int N) {
  int hw = (blockIdx.x * blockDim.x + threadIdx.x) >> 5;
  int lane = threadIdx.x & 31;
  if (hw >= N) return;
  int i = hw;
  int c0 = lane * 4;
  float di = dis[i];
  int beg = offsets[i], end = offsets[i + 1];
  float ax = 0.f, ay = 0.f, az = 0.f, aw = 0.f;
  int e = beg;
  for (; e + 8 <= end; e += 8) {
    int s0 = csr_src[e],     s1 = csr_src[e + 1], s2 = csr_src[e + 2], s3 = csr_src[e + 3];
    int s4 = csr_src[e + 4], s5 = csr_src[e + 5], s6 = csr_src[e + 6], s7 = csr_src[e + 7];
    float w0 = dis[s0], w1 = dis[s1], w2 = dis[s2], w3 = dis[s3];
    float w4 = dis[s4], w5 = dis[s5], w6 = dis[s6], w7 = dis[s7];
    const float4 y0 = *(const float4*)(x + (size_t)s0 * HD + c0);
    const float4 y1 = *(const float4*)(x + (size_t)s1 * HD + c0);
    const float4 y2 = *(const float4*)(x + (size_t)s2 * HD + c0);
    const float4 y3 = *(const float4*)(x + (size_t)s3 * HD + c0);
    const float4 y4 = *(const float4*)(x + (size_t)s4 * HD + c0);
    const float4 y5 = *(const float4*)(x + (size_t)s5 * HD + c0);
    const float4 y6 = *(const float4*)(x + (size_t)s6 * HD + c0);
    const float4 y7 = *(const float4*)(x + (size_t)s7 * HD + c0);
    ax = fmaf(w0, y0.x, fmaf(w1, y1.x, fmaf(w2, y2.x, fmaf(w3, y3.x, ax))));
    ay = fmaf(w0, y0.y, fmaf(w1, y1.y, fmaf(w2, y2.y, fmaf(w3, y3.y, ay))));
    az = fmaf(w0, y0.z, fmaf(w1, y1.z, fmaf(w2, y2.z, fmaf(w3, y3.z, az))));
    aw = fmaf(w0, y0.w, fmaf(w1, y1.w, fmaf(w2, y2.w, fmaf(w3, y3.w, aw))));
    ax = fmaf(w4, y4.x, fmaf(w5, y5.x, fmaf(w6, y6.x, fmaf(w7, y7.x, ax))));
    ay = fmaf(w4, y4.y, fmaf(w5, y5.y, fmaf(w6, y6.y, fmaf(w7, y7.y, ay))));
    az = fmaf(w4, y4.z, fmaf(w5, y5.z, fmaf(w6, y6.z, fmaf(w7, y7.z, az))));
    aw = fmaf(w4, y4.w, fmaf(w5, y5.w, fmaf(w6, y6.w, fmaf(w7, y7.w, aw))));
  }
  for (; e + 4 <= end; e += 4) {
    int s0 = csr_src[e], s1 = csr_src[e + 1], s2 = csr_src[e + 2], s3 = csr_src[e + 3];
    float w0 = dis[s0], w1 = dis[s1], w2 = dis[s2], w3 = dis[s3];
    const float4 y0 = *(const float4*)(x + (size_t)s0 * HD + c0);
    const float4 y1 = *(const float4*)(x + (size_t)s1 * HD + c0);
    const float4 y2 = *(const float4*)(x + (size_t)s2 * HD + c0);
    const float4 y3 = *(const float4*)(x + (size_t)s3 * HD + c0);
    ax = fmaf(w0, y0.x, fmaf(w1, y1.x, fmaf(w2, y2.x, fmaf(w3, y3.x, ax))));
    ay = fmaf(w0, y0.y, fmaf(w1, y1.y, fmaf(w2, y2.y, fmaf(w3, y3.y, ay))));
    az = fmaf(w0, y0.z, fmaf(w1, y1.z, fmaf(w2, y2.z, fmaf(w3, y3.z, az))));
    aw = fmaf(w0, y0.w, fmaf(w1, y1.w, fmaf(w2, y2.w, fmaf(w3, y3.w, aw))));
  }
  for (; e < end; ++e) {
    int s = csr_src[e];
    float w = dis[s];
    const float4 ys = *(const float4*)(x + (size_t)s * HD + c0);
    ax = fmaf(w, ys.x, ax);
    ay = fmaf(w, ys.y, ay);
    az = fmaf(w, ys.z, az);
    aw = fmaf(w, ys.w, aw);
  }
  const float4 xi = *(const float4*)(x + (size_t)i * HD + c0);
  float inv = di * di;
  float4 o = make_float4(di * ax + inv * xi.x, di * ay + inv * xi.y,
                         di * az + inv * xi.z, di * aw + inv * xi.w);
  *(float4*)(T + (size_t)i * HD + c0) = o;
}

// ---------------- 3-way-split bf16 MFMA GEMM v2: NO LDS, direct-global fragments ----------
// Each thread owns a unique (w, lr, lg) fragment tuple: A-fragment = 8 contiguous floats
// of row r0+16w+lr at k = kb*32+8lg -> direct global load (per wave: 16 rows x 128
// contiguous bytes, fully coalesced, L2-hot) + in-register 3-way split. No LDS, no
// bank conflicts, no per-kb barriers. ONE barrier before the in-place epilogue
// (all A-reads precede all writes). 64-row tiles -> 2048 blocks -> full occupancy.
// Products kept: hh+hm+mh+hl+mm+lh (dropped ~2^-27 rel); absmax measured 7.6e-6 (R15).
__global__ __launch_bounds__(256) void gemm_mfma_kernel(
    float* __restrict__ T, const ushort* __restrict__ WhT, const ushort* __restrict__ WmT,
    const ushort* __restrict__ WlT, const float* __restrict__ b, int N) {
  int t = threadIdx.x;
  int r0 = blockIdx.x * 64;
  int w = t >> 6, l = t & 63;
  int lr = l & 15, lg = l >> 4;
  int arow = r0 + 16 * w + lr;
  f32x4 acc[8];
#pragma unroll
  for (int n = 0; n < 8; ++n) acc[n] = (f32x4){0.f, 0.f, 0.f, 0.f};

#pragma unroll
  for (int kb = 0; kb < 4; ++kb) {
    const float* src = T + (size_t)arow * HD + kb * 32 + 8 * lg;
    float4 v0 = *(const float4*)src;
    float4 v1 = *(const float4*)(src + 4);
    float xs[8] = {v0.x, v0.y, v0.z, v0.w, v1.x, v1.y, v1.z, v1.w};
    bf16x8 fa_h, fa_m, fa_l;
#pragma unroll
    for (int j = 0; j < 8; ++j) {              // static indices (unrolled) -> stays in VGPRs
      ushort h = bf16_rne(xs[j]);
      float r1 = xs[j] - __uint_as_float(((uint32_t)h) << 16);
      ushort m = bf16_rne(r1);
      float r2 = r1 - __uint_as_float(((uint32_t)m) << 16);
      ushort lo = bf16_rne(r2);
      fa_h[j] = (short)h; fa_m[j] = (short)m; fa_l[j] = (short)lo;
    }
    int kk = kb * 32 + 8 * lg;
#pragma unroll
    for (int n = 0; n < 8; ++n) {
      bf16x8 fb_h = *(const bf16x8*)(WhT + (size_t)(16 * n + lr) * 128 + kk);
      bf16x8 fb_m = *(const bf16x8*)(WmT + (size_t)(16 * n + lr) * 128 + kk);
      bf16x8 fb_l = *(const bf16x8*)(WlT + (size_t)(16 * n + lr) * 128 + kk);
      acc[n] = __builtin_amdgcn_mfma_f32_16x16x32_bf16(fa_h, fb_h, acc[n], 0, 0, 0);
      acc[n] = __builtin_amdgcn_mfma_f32_16x16x32_bf16(fa_h, fb_m, acc[n], 0, 0, 0);
      acc[n] = __builtin_amdgcn_mfma_f32_16x16x32_bf16(fa_m, fb_h, acc[n], 0, 0, 0);
      acc[n] = __builtin_amdgcn_mfma_f32_16x16x32_bf16(fa_h, fb_l, acc[n], 0, 0, 0);
      acc[n] = __builtin_amdgcn_mfma_f32_16x16x32_bf16(fa_m, fb_m, acc[n], 0, 0, 0);
      acc[n] = __builtin_amdgcn_mfma_f32_16x16x32_bf16(fa_l, fb_h, acc[n], 0, 0, 0);
    }
  }

  __syncthreads();   // in-place safety: every thread's A-reads done before any write

  // epilogue: bias + tanh; D[col=lr][row=4*lg+r] per 16x16 tile (m89-verified layout)
#pragma unroll
  for (int n = 0; n < 8; ++n) {
    float bc = b[16 * n + lr];
#pragma unroll
    for (int r = 0; r < 4; ++r) {
      int row = r0 + 16 * w + 4 * lg + r;
      T[(size_t)row * HD + 16 * n + lr] = tanhf(acc[n][r] + bc);
    }
  }
}

// ---------------- per-graph start offsets ----------------
__global__ void gstart_kernel(const int* __restrict__ batch, int* __restrict__ gstart,
                              int N, int B) {
  int g = blockIdx.x * blockDim.x + threadIdx.x;
  if (g > B) return;
  int lo = 0, hi = N;
  while (lo < hi) { int mid = (lo + hi) >> 1; if (batch[mid] < g) lo = mid + 1; else hi = mid; }
  gstart[g] = lo;
}

// ---------------- sort-pool + conv head, one block per graph, 512 threads ----------------
__global__ __launch_bounds__(512) void head_kernel(
    const float* __restrict__ X1, const float* __restrict__ X2, const float* __restrict__ X3,
    const int* __restrict__ gstart,
    const float* __restrict__ Wc1, const float* __restrict__ bc1,
    const float* __restrict__ Wc2, const float* __restrict__ bc2,
    const float* __restrict__ g1, const float* __restrict__ be1,
    const float* __restrict__ g2, const float* __restrict__ be2,
    const float* __restrict__ rm1, const float* __restrict__ rv1,
    const float* __restrict__ rm2, const float* __restrict__ rv2,
    const float* __restrict__ Wl1, const float* __restrict__ bl1,
    const float* __restrict__ Wl2, const float* __restrict__ bl2,
    float* __restrict__ out) {
  constexpr int MAXC = 512;
  __shared__ float vals[MAXC];
  __shared__ int   sel[KK];
  __shared__ float ph[KK][385];
  __shared__ float h1b[C1N][KK + 1];
  float* h2b  = &ph[0][0];
  float* pp   = &ph[0][0] + 832;
  float* part = &ph[0][0] + 1248;
  float* l1v  = &ph[0][0] + 1760;

  int g = blockIdx.x, t = threadIdx.x;
  int start = gstart[g];
  int count = gstart[g + 1] - start;
  if (count > MAXC) count = MAXC;
  int kk = count < KK ? count : KK;

  for (int i = t; i < count; i += 512)
    vals[i] = X3[(size_t)(start + i) * HD + (HD - 1)];
  __syncthreads();
  if (t < count) {
    float vi = vals[t];
    int rank = 0;
    for (int j = 0; j < count; ++j) {
      float vj = vals[j];
      rank += (vj > vi) || (vj == vi && j < t);
    }
    if (rank < KK) sel[rank] = t;
  }
  __syncthreads();

  for (int l = t; l < KK * DD; l += 512) {
    int r = l / DD, d = l - r * DD;
    float v = 0.f;
    if (r < kk) {
      size_t n = (size_t)(start + sel[r]);
      v = (d < HD) ? X1[n * HD + d]
        : (d < 2 * HD) ? X2[n * HD + (d - HD)]
                       : X3[n * HD + (d - 2 * HD)];
    }
    ph[r][d] = v;
  }
  __syncthreads();

  if (t < C1N * KK) {
    int c = t / KK, k = t - c * KK;
    const float* w = Wc1 + c * DD;
    float s = bc1[c];
    for (int d = 0; d < DD; ++d) s = fmaf(ph[k][d], w[d], s);
    s = fmaxf(s, 0.f);
    float sc = g1[c] * rsqrtf(rv1[c] + 1e-5f);
    h1b[c][k] = (s - rm1[c]) * sc + be1[c];
  }
  __syncthreads();

  for (int l = t; l < C2N * CONVL; l += 512) {
    int o = l / CONVL, tt = l - o * CONVL;
    float s = bc2[o];
    const float* w = Wc2 + o * (C1N * KERN5);
#pragma unroll
    for (int c = 0; c < C1N; ++c)
#pragma unroll
      for (int q = 0; q < KERN5; ++q)
        s = fmaf(h1b[c][tt + q], w[c * KERN5 + q], s);
    s = fmaxf(s, 0.f);
    float sc = g2[o] * rsqrtf(rv2[o] + 1e-5f);
    h2b[o * CONVL + tt] = (s - rm2[o]) * sc + be2[o];
  }
  __syncthreads();

  if (t < FLAT) {
    int o = t / PL, u = t - o * PL;
    pp[t] = fmaxf(h2b[o * CONVL + 2 * u], h2b[o * CONVL + 2 * u + 1]);
  }
  __syncthreads();

  {
    int j = t & 127, h = t >> 7;
    const int Q = FLAT / 4;
    const float* w = Wl1 + (size_t)j * FLAT + h * Q;
    float s = (h == 0) ? bl1[j] : 0.f;
    for (int f = 0; f < Q; ++f) s = fmaf(pp[h * Q + f], w[f], s);
    part[t] = s;
  }
  __syncthreads();
  if (t < 128) l1v[t] = fmaxf(part[t] + part[t + 128] + part[t + 256] + part[t + 384], 0.f);
  __syncthreads();

  if (t < 64) {
    float s = l1v[t] * Wl2[t] + l1v[t + 64] * Wl2[t + 64];
#pragma unroll
    for (int o2 = 32; o2 > 0; o2 >>= 1) s += __shfl_down(s, o2);
    if (t == 0) out[g] = s + bl2[0];
  }
}

extern "C" void kernel_launch(void* const* d_in, const int* in_sizes, int n_in,
                              void* d_out, int out_size, void* d_ws, size_t ws_size,
                              hipStream_t stream) {
  const int*   z    = (const int*)d_in[0];
  const int*   ei   = (const int*)d_in[1];
  const int*   batch= (const int*)d_in[2];
  const float* W0   = (const float*)d_in[3];
  const float* b0   = (const float*)d_in[4];
  const float* W1   = (const float*)d_in[5];
  const float* b1   = (const float*)d_in[6];
  const float* W2   = (const float*)d_in[7];
  const float* b2   = (const float*)d_in[8];
  const float* Wc1  = (const float*)d_in[9];
  const float* bc1  = (const float*)d_in[10];
  const float* Wc2  = (const float*)d_in[11];
  const float* bc2  = (const float*)d_in[12];
  const float* g1   = (const float*)d_in[13];
  const float* be1  = (const float*)d_in[14];
  const float* g2   = (const float*)d_in[15];
  const float* be2  = (const float*)d_in[16];
  const float* Wl1  = (const float*)d_in[17];
  const float* bl1  = (const float*)d_in[18];
  const float* Wl2  = (const float*)d_in[19];
  const float* bl2  = (const float*)d_in[20];
  const float* rm1  = (const float*)d_in[21];
  const float* rv1  = (const float*)d_in[22];
  const float* rm2  = (const float*)d_in[23];
  const float* rv2  = (const float*)d_in[24];

  const int N = in_sizes[0];
  const int E = in_sizes[1] / 2;
  const int B = out_size;
  const int* rowp = ei;       // edge_index[0] = source
  const int* colp = ei + E;   // edge_index[1] = target

  char* base = (char*)d_ws;
  size_t off = 0;
  auto alloc = [&](size_t bytes) -> void* {
    void* p = base + off;
    off += (bytes + 255) & ~(size_t)255;
    return p;
  };
  int*    cnt     = (int*)alloc((size_t)N * 4);
  int*    offsets = (int*)alloc(((size_t)N + 1) * 4);
  int*    cursor  = (int*)alloc((size_t)N * 4);
  int*    csr_src = (int*)alloc((size_t)E * 4);
  float*  dis     = (float*)alloc((size_t)N * 4);
  int*    gstart  = (int*)alloc(((size_t)B + 1) * 4);
  int*    bsum    = (int*)alloc(1024 * 4);
  ushort* WhT1    = (ushort*)alloc(128 * 128 * 2);
  ushort* WmT1    = (ushort*)alloc(128 * 128 * 2);
  ushort* WlT1    = (ushort*)alloc(128 * 128 * 2);
  ushort* WhT2    = (ushort*)alloc(128 * 128 * 2);
  ushort* WmT2    = (ushort*)alloc(128 * 128 * 2);
  ushort* WlT2    = (ushort*)alloc(128 * 128 * 2);
  float*  X1      = (float*)alloc((size_t)N * HD * 4);
  float*  X2      = (float*)alloc((size_t)N * HD * 4);
  float*  X3      = (float*)alloc((size_t)N * HD * 4);
  (void)ws_size; (void)n_in;

  hipMemsetAsync(cnt, 0, (size_t)N * 4, stream);
  hipMemsetAsync(cursor, 0, (size_t)N * 4, stream);

  const int nb = (N + 1023) / 1024;
  deg_kernel<<<(E + 255) / 256, 256, 0, stream>>>(colp, cnt, E);
  scan1_kernel<<<nb, 256, 0, stream>>>(cnt, bsum, N);
  scan2_kernel<<<1, 1024, 0, stream>>>(bsum, nb);
  scan3_kernel<<<nb, 256, 0, stream>>>(cnt, bsum, offsets, dis, N);
  fill_kernel<<<(E + 255) / 256, 256, 0, stream>>>(rowp, colp, offsets, cursor, csr_src, E);
  wprep_kernel<<<64, 256, 0, stream>>>(W1, WhT1, WmT1, WlT1);
  wprep_kernel<<<64, 256, 0, stream>>>(W2, WhT2, WmT2, WlT2);

  // layer 0: onehot(z)@W0 == W0[z], fused into aggregation, tanh inside
  agg0_kernel<<<N / 8, 256, 0, stream>>>(z, offsets, csr_src, dis, W0, b0, X1, N);
  // layer 1: aggregate-first (half-wave gather), then in-place 3-way-split MFMA GEMM
  agg_kernel<<<N / 8, 256, 0, stream>>>(X1, offsets, csr_src, dis, X2, N);
  gemm_mfma_kernel<<<N / 64, 256, 0, stream>>>(X2, WhT1, WmT1, WlT1, b1, N);
  // layer 2
  agg_kernel<<<N / 8, 256, 0, stream>>>(X2, offsets, csr_src, dis, X3, N);
  gemm_mfma_kernel<<<N / 64, 256, 0, stream>>>(X3, WhT2, WmT2, WlT2, b2, N);

  gstart_kernel<<<(B + 1 + 255) / 256, 256, 0, stream>>>(batch, gstart, N, B);
  head_kernel<<<B, 512, 0, stream>>>(X1, X2, X3, gstart, Wc1, bc1, Wc2, bc2, g1, be1, g2, be2,
                                     rm1, rv1, rm2, rv2, Wl1, bl1, Wl2, bl2, (float*)d_out);
}